// Round 1
// 456.193 us; speedup vs baseline: 1.0652x; 1.0652x over previous
//
#include <hip/hip_runtime.h>
#include <cmath>

#define D_K 768
#define GK 640
#define KC_N 24          // 768/32 k-chunks
#define HALF_TILE 10240  // halves: 20 nc * 64 lanes * 8
#define TILE_HALVES 20480 // hi+lo tile per (kc, group) = 40960 B

typedef _Float16 f16x8 __attribute__((ext_vector_type(8)));
typedef float f32x4 __attribute__((ext_vector_type(4)));

typedef __attribute__((address_space(1))) const void* as1cv;
typedef __attribute__((address_space(3))) void* as3v;

// ---------------- prep: zero bins + swizzle W (fp32 -> fp16 hi/lo, MFMA B-frag order) ----------------
// WB layout: [kc][g][h(hi/lo)][ncl(20)][lane(64)][j(8)] halves.
// lane supplies B[k = kc*32 + (lane>>4)*8 + j][n = (g*20+ncl)*16 + (lane&15)]
__global__ __launch_bounds__(256) void prep_kernel(const float* __restrict__ W,
        unsigned* __restrict__ bins, _Float16* __restrict__ WB) {
    int t = blockIdx.x * 256 + threadIdx.x;   // 240*256 = 61440 = 960 frags * 64 lanes
    if (t < 1280) bins[t] = 0u;               // counts[640] u32 + probsum[640] f32 (0 bits)
    int fid = t >> 6;
    int l = t & 63;
    int kc = fid / 40, nc = fid - kc * 40;
    int g = nc / 20, ncl = nc - g * 20;
    int n = nc * 16 + (l & 15);
    int k0 = kc * 32 + (l >> 4) * 8;
    f16x8 hi, lo;
#pragma unroll
    for (int j = 0; j < 8; ++j) {
        float wv = W[(size_t)(k0 + j) * GK + n];
        _Float16 h = (_Float16)wv;
        hi[j] = h;
        lo[j] = (_Float16)(wv - (float)h);
    }
    size_t base = (size_t)(kc * 2 + g) * TILE_HALVES + ncl * 512 + l * 8;
    *(f16x8*)(WB + base) = hi;
    *(f16x8*)(WB + base + HALF_TILE) = lo;
}

// ---------------- main: 128 rows x 320 cols (one group) per block, 16 waves ----------------
// wave w: mch = w>>2 (rows mch*32..+31, 2 chunks of 16), slice s = w&3 (cols s*80..+79 in group).
// B comes from LDS, staged once per (block, kc) via async global_load_lds (shared by 16 waves).
// grid 512: g = bx>>8 so both group-blocks of a row-stripe land on the same XCD (bx%8 preserved).
__global__ __launch_bounds__(1024, 4) void main_kernel(
        const float* __restrict__ x, const float* __restrict__ bias,
        const float* __restrict__ noise, const float* __restrict__ cb,
        const _Float16* __restrict__ WB,
        float* __restrict__ out, unsigned* __restrict__ counts, float* __restrict__ probsum)
{
    __shared__ __align__(16) _Float16 sB[TILE_HALVES];   // 40 KB single-buffer B tile
    __shared__ float s_pmax[4][128];
    __shared__ int   s_pcol[4][128];
    __shared__ float s_pgmax[4][128];
    __shared__ int   s_pgcol[4][128];
    __shared__ float s_psum[4][128];
    __shared__ float s_fmax[128];
    __shared__ float s_fsum[128];
    __shared__ int   s_fgcol[128];
    __shared__ float s_bins[320];

    int tid = threadIdx.x;
    int bx = blockIdx.x;
    int g  = bx >> 8;            // group 0/1
    int rb = bx & 255;
    int r0 = rb * 128;
    int w = tid >> 6;
    int l = tid & 63;
    int lrow = l >> 4;           // quad 0..3
    int lcol = l & 15;
    int mch = w >> 2;            // 0..3
    int s = w & 3;               // col slice
    int s5 = s * 5;

    f32x4 acc[2][5];
#pragma unroll
    for (int i = 0; i < 2; ++i)
#pragma unroll
        for (int j = 0; j < 5; ++j) acc[i][j] = (f32x4){0.f, 0.f, 0.f, 0.f};

    // A: lane holds A[m=lane&15][k=quad*8+j]; chunk i row = r0 + mch*32 + i*16 + lcol
    const float* xb0 = x + (size_t)(r0 + mch * 32 + lcol) * D_K + lrow * 8;
    const float* xb1 = xb0 + 16 * D_K;

    // async stage of the (kc, g) B tile: 40960 B = 2560 x 16 B, 1024 threads
    auto stage = [&](int kc) {
        const char* src = (const char*)(WB + (size_t)(kc * 2 + g) * TILE_HALVES);
        char* dst = (char*)sB;
#pragma unroll
        for (int kk = 0; kk < 2; ++kk) {
            int u = tid + kk * 1024;
            __builtin_amdgcn_global_load_lds((as1cv)(src + (size_t)u * 16),
                                             (as3v)(dst + u * 16), 16, 0, 0);
        }
        if (tid < 512) {                      // waves 0..7 whole -> wave-uniform
            int u = tid + 2048;
            __builtin_amdgcn_global_load_lds((as1cv)(src + (size_t)u * 16),
                                             (as3v)(dst + u * 16), 16, 0, 0);
        }
    };

    stage(0);
    f32x4 a00 = *(const f32x4*)xb0, a01 = *(const f32x4*)(xb0 + 4);
    f32x4 a10 = *(const f32x4*)xb1, a11 = *(const f32x4*)(xb1 + 4);

    for (int kc = 0; kc < KC_N; ++kc) {
        // 1) convert current A (VALU; overlaps stage latency before the barrier)
        f16x8 ah[2], al[2];
#pragma unroll
        for (int j = 0; j < 4; ++j) {
            float f;
            _Float16 h;
            f = a00[j]; h = (_Float16)f; ah[0][j] = h;     al[0][j] = (_Float16)(f - (float)h);
            f = a01[j]; h = (_Float16)f; ah[0][4 + j] = h; al[0][4 + j] = (_Float16)(f - (float)h);
            f = a10[j]; h = (_Float16)f; ah[1][j] = h;     al[1][j] = (_Float16)(f - (float)h);
            f = a11[j]; h = (_Float16)f; ah[1][4 + j] = h; al[1][4 + j] = (_Float16)(f - (float)h);
        }
        __syncthreads();    // B tile kc visible; prior readers done

        // 2) A prefetch for next kc — drained at the barrier AFTER the long MFMA phase
        int kn = (kc < KC_N - 1) ? kc + 1 : 0;
        f32x4 n00 = *(const f32x4*)(xb0 + kn * 32), n01 = *(const f32x4*)(xb0 + kn * 32 + 4);
        f32x4 n10 = *(const f32x4*)(xb1 + kn * 32), n11 = *(const f32x4*)(xb1 + kn * 32 + 4);

        // 3) MFMA: 3-product fp16x2 (hh + lh + hl), B frags from LDS (ds_read_b128, stride-1)
#pragma unroll
        for (int j = 0; j < 5; ++j) {
            int ncl = s5 + j;
            f16x8 bh = *(const f16x8*)(sB + ncl * 512 + l * 8);
            f16x8 bl = *(const f16x8*)(sB + HALF_TILE + ncl * 512 + l * 8);
            acc[0][j] = __builtin_amdgcn_mfma_f32_16x16x32_f16(ah[0], bh, acc[0][j], 0, 0, 0);
            acc[0][j] = __builtin_amdgcn_mfma_f32_16x16x32_f16(al[0], bh, acc[0][j], 0, 0, 0);
            acc[0][j] = __builtin_amdgcn_mfma_f32_16x16x32_f16(ah[0], bl, acc[0][j], 0, 0, 0);
            acc[1][j] = __builtin_amdgcn_mfma_f32_16x16x32_f16(ah[1], bh, acc[1][j], 0, 0, 0);
            acc[1][j] = __builtin_amdgcn_mfma_f32_16x16x32_f16(al[1], bh, acc[1][j], 0, 0, 0);
            acc[1][j] = __builtin_amdgcn_mfma_f32_16x16x32_f16(ah[1], bl, acc[1][j], 0, 0, 0);
        }
        __syncthreads();    // all waves finished reading tile kc
        if (kc < KC_N - 1) stage(kc + 1);     // async fill for next iter
        a00 = n00; a01 = n01; a10 = n10; a11 = n11;
    }

    // bias (zeros in setup, kept for correctness)
#pragma unroll
    for (int j = 0; j < 5; ++j) {
        float bb = bias[g * 320 + (s5 + j) * 16 + lcol];
#pragma unroll
        for (int i = 0; i < 2; ++i)
#pragma unroll
            for (int r = 0; r < 4; ++r) acc[i][j][r] += bb;
    }

    // ---------------- epilogue (one group per block; cols are local 0..319) ----------------
    // E1: per-wave partial (max,argmax) of logits and logits+gumbel over the 80-col slice
#pragma unroll
    for (int i = 0; i < 2; ++i) {
#pragma unroll
        for (int r = 0; r < 4; ++r) {
            int row = mch * 32 + i * 16 + lrow * 4 + r;   // C/D: row = quad*4 + reg, col = lane&15
            float vmax = -3.4e38f; int vcol = 0;
            float gmax = -3.4e38f; int gcol = 0;
            const float* np = noise + (size_t)(r0 + row) * GK + g * 320 + s5 * 16 + lcol;
#pragma unroll
            for (int j = 0; j < 5; ++j) {
                float v = acc[i][j][r];
                int c = (s5 + j) * 16 + lcol;             // local col in group
                if (v > vmax) { vmax = v; vcol = c; }
                float u = np[j * 16] * (1.0f - 2e-6f) + 1e-6f;
                float gn = -__logf(-__logf(u));
                float z = v + gn;     // argmax((logits+g)/TAU) == argmax(logits+g)
                if (z > gmax) { gmax = z; gcol = c; }
            }
#pragma unroll
            for (int off = 1; off < 16; off <<= 1) {
                float ov = __shfl_xor(vmax, off); int oc = __shfl_xor(vcol, off);
                if (ov > vmax || (ov == vmax && oc < vcol)) { vmax = ov; vcol = oc; }
                float og = __shfl_xor(gmax, off); int ogc = __shfl_xor(gcol, off);
                if (og > gmax || (og == gmax && ogc < gcol)) { gmax = og; gcol = ogc; }
            }
            if (lcol == 0) {
                s_pmax[s][row] = vmax; s_pcol[s][row] = vcol;
                s_pgmax[s][row] = gmax; s_pgcol[s][row] = gcol;
            }
        }
    }
    if (tid < 320) s_bins[tid] = 0.0f;
    __syncthreads();

    // E2: combine 4 slices per row (ascending col = reference tie-break); hard-count atomic
    if (tid < 128) {
        int row = tid;
        float vmax = -3.4e38f; int vcol = 0;
        float gmax = -3.4e38f; int gcol = 0;
        for (int ss = 0; ss < 4; ++ss) {
            float v = s_pmax[ss][row];
            if (v > vmax) { vmax = v; vcol = s_pcol[ss][row]; }
            float z = s_pgmax[ss][row];
            if (z > gmax) { gmax = z; gcol = s_pgcol[ss][row]; }
        }
        s_fmax[row] = vmax;
        s_fgcol[row] = gcol;
        atomicAdd(&counts[g * 320 + vcol], 1u);
    }
    __syncthreads();

    // E3: exp-sum per row
#pragma unroll
    for (int i = 0; i < 2; ++i) {
#pragma unroll
        for (int r = 0; r < 4; ++r) {
            int row = mch * 32 + i * 16 + lrow * 4 + r;
            float M = s_fmax[row];
            float sm = 0.f;
#pragma unroll
            for (int j = 0; j < 5; ++j) sm += __expf(acc[i][j][r] - M);
#pragma unroll
            for (int off = 1; off < 16; off <<= 1) sm += __shfl_xor(sm, off);
            if (lcol == 0) s_psum[s][row] = sm;
        }
    }
    __syncthreads();
    if (tid < 128) {
        float S = 0.f;
        for (int ss = 0; ss < 4; ++ss) S += s_psum[ss][tid];
        s_fsum[tid] = S;
    }
    __syncthreads();

    // E4: softmax probs into LDS bins, then one global atomic per bin
#pragma unroll
    for (int i = 0; i < 2; ++i) {
#pragma unroll
        for (int r = 0; r < 4; ++r) {
            int row = mch * 32 + i * 16 + lrow * 4 + r;
            float M = s_fmax[row];
            float invS = 1.0f / s_fsum[row];
#pragma unroll
            for (int j = 0; j < 5; ++j)
                atomicAdd(&s_bins[(s5 + j) * 16 + lcol], __expf(acc[i][j][r] - M) * invS);
        }
    }
    __syncthreads();
    if (tid < 320) atomicAdd(&probsum[g * 320 + tid], s_bins[tid]);

    // E5: out[row, g*128:(g+1)*128] = cb[winner, :]  (y == y_hard in forward)
    {
        int row = tid >> 3, jj = tid & 7;     // 128 teams of 8 threads
        int wcol = g * 320 + s_fgcol[row];
        const f32x4* src = (const f32x4*)(cb + (size_t)wcol * 128);
        f32x4* dst = (f32x4*)(out + (size_t)(r0 + row) * 256 + g * 128);
#pragma unroll
        for (int k = 0; k < 4; ++k) dst[k * 8 + jj] = src[k * 8 + jj];
    }
}

// ---------------- finalize: perplexities (parallel reduction) ----------------
__global__ __launch_bounds__(640) void fin_kernel(const unsigned* __restrict__ counts,
        const float* __restrict__ probsum, float* __restrict__ out2) {
    __shared__ float sh[640], sp[640], sred[4];
    int t = threadIdx.x;
    float ph = (float)counts[t] * (1.0f / 32768.0f);
    sh[t] = ph * logf(ph + 1e-7f);
    float pp = probsum[t] * (1.0f / 32768.0f);
    sp[t] = pp * logf(pp + 1e-7f);
    __syncthreads();
    if (t < 256) {
        int seg = t >> 6;               // 0:sh g0, 1:sh g1, 2:sp g0, 3:sp g1
        int l = t & 63;
        const float* sv = (seg & 2) ? sp : sh;
        int base = (seg & 1) * 320;
        float v = 0.f;
#pragma unroll
        for (int k = 0; k < 5; ++k) v += sv[base + l + 64 * k];
#pragma unroll
        for (int off = 1; off < 64; off <<= 1) v += __shfl_xor(v, off);
        if (l == 0) sred[seg] = v;
    }
    __syncthreads();
    if (t < 2) out2[t] = expf(-sred[t * 2]) + expf(-sred[t * 2 + 1]);
}

extern "C" void kernel_launch(void* const* d_in, const int* in_sizes, int n_in,
                              void* d_out, int out_size, void* d_ws, size_t ws_size,
                              hipStream_t stream) {
    const float* x     = (const float*)d_in[0];   // [16,2048,768]
    const float* W     = (const float*)d_in[1];   // [768,640]
    const float* b     = (const float*)d_in[2];   // [640]
    const float* cb    = (const float*)d_in[3];   // [1,640,128]
    const float* noise = (const float*)d_in[4];   // [32768,2,320]
    float* out = (float*)d_out;                   // 16*2048*256 floats + 2 scalars

    char* ws = (char*)d_ws;
    unsigned* counts = (unsigned*)ws;             // [640] u32
    float* probsum   = (float*)(ws + 2560);       // [640] f32
    _Float16* WB     = (_Float16*)(ws + 8192);    // 24*2*20480 halves = 1966080 B

    hipLaunchKernelGGL(prep_kernel, dim3(240), dim3(256), 0, stream, W, counts, WB);
    hipLaunchKernelGGL(main_kernel, dim3(512), dim3(1024), 0, stream,
                       x, b, noise, cb, WB, out, counts, probsum);
    hipLaunchKernelGGL(fin_kernel, dim3(1), dim3(640), 0, stream, counts, probsum, out + 8388608);
}

// Round 3
// 364.844 us; speedup vs baseline: 1.3319x; 1.2504x over previous
//
#include <hip/hip_runtime.h>
#include <cmath>

#define D_K 768
#define GK 640
#define KC_N 24           // 768/32 k-chunks
#define HALF_TILE 10240   // halves: 20 nc * 64 lanes * 8
#define TILE_HALVES 20480 // hi+lo tile per (kc, group) = 40960 B

typedef _Float16 f16x8 __attribute__((ext_vector_type(8)));
typedef float f32x4 __attribute__((ext_vector_type(4)));

typedef __attribute__((address_space(1))) const void* as1cv;
typedef __attribute__((address_space(3))) void* as3v;

// ---------------- prep: zero bins + swizzle W (fp32 -> fp16 hi/lo, MFMA B-frag order) ----------------
// WB layout: [kc][g][h(hi/lo)][ncl(20)][lane(64)][j(8)] halves.
// lane supplies B[k = kc*32 + (lane>>4)*8 + j][n = (g*20+ncl)*16 + (lane&15)]
__global__ __launch_bounds__(256) void prep_kernel(const float* __restrict__ W,
        unsigned* __restrict__ bins, _Float16* __restrict__ WB) {
    int t = blockIdx.x * 256 + threadIdx.x;   // 240*256 = 61440 = 960 frags * 64 lanes
    if (t < 1280) bins[t] = 0u;               // counts[640] u32 + probsum[640] f32 (0 bits)
    int fid = t >> 6;
    int l = t & 63;
    int kc = fid / 40, nc = fid - kc * 40;
    int g = nc / 20, ncl = nc - g * 20;
    int n = nc * 16 + (l & 15);
    int k0 = kc * 32 + (l >> 4) * 8;
    f16x8 hi, lo;
#pragma unroll
    for (int j = 0; j < 8; ++j) {
        float wv = W[(size_t)(k0 + j) * GK + n];
        _Float16 h = (_Float16)wv;
        hi[j] = h;
        lo[j] = (_Float16)(wv - (float)h);
    }
    size_t base = (size_t)(kc * 2 + g) * TILE_HALVES + ncl * 512 + l * 8;
    *(f16x8*)(WB + base) = hi;
    *(f16x8*)(WB + base + HALF_TILE) = lo;
}

// ---------------- main: 64 rows x 320 cols (one group) per block, 8 waves ----------------
// wave w: mch = w>>2 (rows mch*32..+31, 2 chunks of 16), slice s = w&3 (cols s*80..+79).
// B staged in LDS per (block, kc) via async global_load_lds; epilogue LDS arrays OVERLAY the
// dead B tile, keeping LDS at exactly 40960 B so multiple blocks co-reside per CU — one
// block's barrier/epilogue stalls overlap another's MFMA phase.
// blockIdx mapping: the (g=0,g=1) blocks of one row-stripe are bx and bx+8 -> same XCD
// (round-robin %8), so the pair shares its x reads in that XCD's L2.
__global__ __launch_bounds__(512, 4) void main_kernel(
        const float* __restrict__ x, const float* __restrict__ bias,
        const float* __restrict__ noise, const float* __restrict__ cb,
        const _Float16* __restrict__ WB,
        float* __restrict__ out, unsigned* __restrict__ counts, float* __restrict__ probsum)
{
    __shared__ __align__(16) char smem[40960];
    _Float16* sB = (_Float16*)smem;                       // K-loop B tile (full 40960 B)
    // epilogue overlays (valid only after the final K-loop barrier):
    float (*s_pmax)[64]  = (float(*)[64])(smem);          // 1024 B
    int   (*s_pcol)[64]  = (int(*)[64])(smem + 1024);     // 1024 B
    float (*s_pgmax)[64] = (float(*)[64])(smem + 2048);   // 1024 B
    int   (*s_pgcol)[64] = (int(*)[64])(smem + 3072);     // 1024 B
    float (*s_psum)[64]  = (float(*)[64])(smem + 4096);   // 1024 B
    float* s_fmax  = (float*)(smem + 5120);               // 256 B
    float* s_fsum  = (float*)(smem + 5376);               // 256 B
    int*   s_fgcol = (int*)(smem + 5632);                 // 256 B
    float* s_bins  = (float*)(smem + 5888);               // 1280 B  (end 7168 < 40960)

    int tid = threadIdx.x;
    int bx = blockIdx.x;
    int g  = (bx >> 3) & 1;                  // group 0/1
    int rb = (bx & 7) | ((bx >> 4) << 3);    // row-stripe 0..511
    int r0 = rb * 64;
    int w = tid >> 6;
    int l = tid & 63;
    int lrow = l >> 4;       // quad 0..3
    int lcol = l & 15;
    int mch = w >> 2;        // 0/1
    int s = w & 3;           // col slice
    int s5 = s * 5;

    f32x4 acc[2][5];
#pragma unroll
    for (int i = 0; i < 2; ++i)
#pragma unroll
        for (int j = 0; j < 5; ++j) acc[i][j] = (f32x4){0.f, 0.f, 0.f, 0.f};

    // A: lane holds A[m=lane&15][k=quad*8+j]; chunk i row = r0 + mch*32 + i*16 + lcol
    const float* xb0 = x + (size_t)(r0 + mch * 32 + lcol) * D_K + lrow * 8;
    const float* xb1 = xb0 + 16 * D_K;

    // async stage of the (kc, g) B tile: 40960 B = 2560 x 16 B, 512 threads -> 5 each
    auto stage = [&](int kc) {
        const char* src = (const char*)(WB + (size_t)(kc * 2 + g) * TILE_HALVES);
        char* dst = (char*)sB;
#pragma unroll
        for (int kk = 0; kk < 5; ++kk) {
            int u = tid + kk * 512;
            __builtin_amdgcn_global_load_lds((as1cv)(src + (size_t)u * 16),
                                             (as3v)(dst + u * 16), 16, 0, 0);
        }
    };

    stage(0);
    f32x4 a00 = *(const f32x4*)xb0, a01 = *(const f32x4*)(xb0 + 4);
    f32x4 a10 = *(const f32x4*)xb1, a11 = *(const f32x4*)(xb1 + 4);

    for (int kc = 0; kc < KC_N; ++kc) {
        // 1) convert current A (VALU; overlaps stage latency before the barrier)
        f16x8 ah[2], al[2];
#pragma unroll
        for (int j = 0; j < 4; ++j) {
            float f;
            _Float16 h;
            f = a00[j]; h = (_Float16)f; ah[0][j] = h;     al[0][j] = (_Float16)(f - (float)h);
            f = a01[j]; h = (_Float16)f; ah[0][4 + j] = h; al[0][4 + j] = (_Float16)(f - (float)h);
            f = a10[j]; h = (_Float16)f; ah[1][j] = h;     al[1][j] = (_Float16)(f - (float)h);
            f = a11[j]; h = (_Float16)f; ah[1][4 + j] = h; al[1][4 + j] = (_Float16)(f - (float)h);
        }
        __syncthreads();    // B tile kc visible; prior readers done

        // 2) A prefetch for next kc — drained at the barrier AFTER the long MFMA phase
        int kn = (kc < KC_N - 1) ? kc + 1 : 0;
        f32x4 n00 = *(const f32x4*)(xb0 + kn * 32), n01 = *(const f32x4*)(xb0 + kn * 32 + 4);
        f32x4 n10 = *(const f32x4*)(xb1 + kn * 32), n11 = *(const f32x4*)(xb1 + kn * 32 + 4);

        // 3) MFMA: 3-product fp16x2 (hh + lh + hl), B frags from LDS (ds_read_b128, stride-1)
#pragma unroll
        for (int j = 0; j < 5; ++j) {
            int ncl = s5 + j;
            f16x8 bh = *(const f16x8*)(sB + ncl * 512 + l * 8);
            f16x8 bl = *(const f16x8*)(sB + HALF_TILE + ncl * 512 + l * 8);
            acc[0][j] = __builtin_amdgcn_mfma_f32_16x16x32_f16(ah[0], bh, acc[0][j], 0, 0, 0);
            acc[0][j] = __builtin_amdgcn_mfma_f32_16x16x32_f16(al[0], bh, acc[0][j], 0, 0, 0);
            acc[0][j] = __builtin_amdgcn_mfma_f32_16x16x32_f16(ah[0], bl, acc[0][j], 0, 0, 0);
            acc[1][j] = __builtin_amdgcn_mfma_f32_16x16x32_f16(ah[1], bh, acc[1][j], 0, 0, 0);
            acc[1][j] = __builtin_amdgcn_mfma_f32_16x16x32_f16(al[1], bh, acc[1][j], 0, 0, 0);
            acc[1][j] = __builtin_amdgcn_mfma_f32_16x16x32_f16(ah[1], bl, acc[1][j], 0, 0, 0);
        }
        __syncthreads();    // all waves finished reading tile kc (also: epilogue overlay safe)
        if (kc < KC_N - 1) stage(kc + 1);     // async fill for next iter
        a00 = n00; a01 = n01; a10 = n10; a11 = n11;
    }

    // bias (zeros in setup, kept for correctness)
#pragma unroll
    for (int j = 0; j < 5; ++j) {
        float bb = bias[g * 320 + (s5 + j) * 16 + lcol];
#pragma unroll
        for (int i = 0; i < 2; ++i)
#pragma unroll
            for (int r = 0; r < 4; ++r) acc[i][j][r] += bb;
    }

    // ---------------- epilogue (one group per block; cols are local 0..319) ----------------
    // E1: per-wave partial (max,argmax) of logits and logits+gumbel over the 80-col slice
#pragma unroll
    for (int i = 0; i < 2; ++i) {
#pragma unroll
        for (int r = 0; r < 4; ++r) {
            int row = mch * 32 + i * 16 + lrow * 4 + r;   // C/D: row = quad*4 + reg, col = lane&15
            float vmax = -3.4e38f; int vcol = 0;
            float gmax = -3.4e38f; int gcol = 0;
            const float* np = noise + (size_t)(r0 + row) * GK + g * 320 + s5 * 16 + lcol;
#pragma unroll
            for (int j = 0; j < 5; ++j) {
                float v = acc[i][j][r];
                int c = (s5 + j) * 16 + lcol;             // local col in group
                if (v > vmax) { vmax = v; vcol = c; }
                float u = np[j * 16] * (1.0f - 2e-6f) + 1e-6f;
                float gn = -__logf(-__logf(u));
                float z = v + gn;     // argmax((logits+g)/TAU) == argmax(logits+g)
                if (z > gmax) { gmax = z; gcol = c; }
            }
#pragma unroll
            for (int off = 1; off < 16; off <<= 1) {
                float ov = __shfl_xor(vmax, off); int oc = __shfl_xor(vcol, off);
                if (ov > vmax || (ov == vmax && oc < vcol)) { vmax = ov; vcol = oc; }
                float og = __shfl_xor(gmax, off); int ogc = __shfl_xor(gcol, off);
                if (og > gmax || (og == gmax && ogc < gcol)) { gmax = og; gcol = ogc; }
            }
            if (lcol == 0) {
                s_pmax[s][row] = vmax; s_pcol[s][row] = vcol;
                s_pgmax[s][row] = gmax; s_pgcol[s][row] = gcol;
            }
        }
    }
    if (tid < 320) s_bins[tid] = 0.0f;
    __syncthreads();

    // E2: combine 4 slices per row (ascending col = reference tie-break); hard-count atomic
    if (tid < 64) {
        int row = tid;
        float vmax = -3.4e38f; int vcol = 0;
        float gmax = -3.4e38f; int gcol = 0;
        for (int ss = 0; ss < 4; ++ss) {
            float v = s_pmax[ss][row];
            if (v > vmax) { vmax = v; vcol = s_pcol[ss][row]; }
            float z = s_pgmax[ss][row];
            if (z > gmax) { gmax = z; gcol = s_pgcol[ss][row]; }
        }
        s_fmax[row] = vmax;
        s_fgcol[row] = gcol;
        atomicAdd(&counts[g * 320 + vcol], 1u);
    }
    __syncthreads();

    // E3: exp-sum per row
#pragma unroll
    for (int i = 0; i < 2; ++i) {
#pragma unroll
        for (int r = 0; r < 4; ++r) {
            int row = mch * 32 + i * 16 + lrow * 4 + r;
            float M = s_fmax[row];
            float sm = 0.f;
#pragma unroll
            for (int j = 0; j < 5; ++j) sm += __expf(acc[i][j][r] - M);
#pragma unroll
            for (int off = 1; off < 16; off <<= 1) sm += __shfl_xor(sm, off);
            if (lcol == 0) s_psum[s][row] = sm;
        }
    }
    __syncthreads();
    if (tid < 64) {
        float S = 0.f;
        for (int ss = 0; ss < 4; ++ss) S += s_psum[ss][tid];
        s_fsum[tid] = S;
    }
    __syncthreads();

    // E4: per-thread register partials per column, quad-combine via shfl, then ONE
    // collision-free 16-lane LDS atomic per j (replaces 40 colliding LDS atomics/thread)
    {
        float part[5] = {0.f, 0.f, 0.f, 0.f, 0.f};
#pragma unroll
        for (int i = 0; i < 2; ++i) {
#pragma unroll
            for (int r = 0; r < 4; ++r) {
                int row = mch * 32 + i * 16 + lrow * 4 + r;
                float M = s_fmax[row];
                float invS = 1.0f / s_fsum[row];
#pragma unroll
                for (int j = 0; j < 5; ++j)
                    part[j] += __expf(acc[i][j][r] - M) * invS;
            }
        }
#pragma unroll
        for (int j = 0; j < 5; ++j) {
            float p = part[j];
            p += __shfl_xor(p, 16);     // combine lrow bit 0
            p += __shfl_xor(p, 32);     // combine lrow bit 1
            if (lrow == 0) atomicAdd(&s_bins[(s5 + j) * 16 + lcol], p);
        }
    }
    __syncthreads();
    if (tid < 320) atomicAdd(&probsum[g * 320 + tid], s_bins[tid]);

    // E5: out[row, g*128:(g+1)*128] = cb[winner, :]  (y == y_hard in forward)
    {
        int row = tid >> 3, jj = tid & 7;     // 64 teams of 8 threads
        int wcol = g * 320 + s_fgcol[row];
        const f32x4* src = (const f32x4*)(cb + (size_t)wcol * 128);
        f32x4* dst = (f32x4*)(out + (size_t)(r0 + row) * 256 + g * 128);
#pragma unroll
        for (int k = 0; k < 4; ++k) dst[k * 8 + jj] = src[k * 8 + jj];
    }
}

// ---------------- finalize: perplexities (parallel reduction) ----------------
__global__ __launch_bounds__(640) void fin_kernel(const unsigned* __restrict__ counts,
        const float* __restrict__ probsum, float* __restrict__ out2) {
    __shared__ float sh[640], sp[640], sred[4];
    int t = threadIdx.x;
    float ph = (float)counts[t] * (1.0f / 32768.0f);
    sh[t] = ph * logf(ph + 1e-7f);
    float pp = probsum[t] * (1.0f / 32768.0f);
    sp[t] = pp * logf(pp + 1e-7f);
    __syncthreads();
    if (t < 256) {
        int seg = t >> 6;               // 0:sh g0, 1:sh g1, 2:sp g0, 3:sp g1
        int l = t & 63;
        const float* sv = (seg & 2) ? sp : sh;
        int base = (seg & 1) * 320;
        float v = 0.f;
#pragma unroll
        for (int k = 0; k < 5; ++k) v += sv[base + l + 64 * k];
#pragma unroll
        for (int off = 1; off < 64; off <<= 1) v += __shfl_xor(v, off);
        if (l == 0) sred[seg] = v;
    }
    __syncthreads();
    if (t < 2) out2[t] = expf(-sred[t * 2]) + expf(-sred[t * 2 + 1]);
}

extern "C" void kernel_launch(void* const* d_in, const int* in_sizes, int n_in,
                              void* d_out, int out_size, void* d_ws, size_t ws_size,
                              hipStream_t stream) {
    const float* x     = (const float*)d_in[0];   // [16,2048,768]
    const float* W     = (const float*)d_in[1];   // [768,640]
    const float* b     = (const float*)d_in[2];   // [640]
    const float* cb    = (const float*)d_in[3];   // [1,640,128]
    const float* noise = (const float*)d_in[4];   // [32768,2,320]
    float* out = (float*)d_out;                   // 16*2048*256 floats + 2 scalars

    char* ws = (char*)d_ws;
    unsigned* counts = (unsigned*)ws;             // [640] u32
    float* probsum   = (float*)(ws + 2560);       // [640] f32
    _Float16* WB     = (_Float16*)(ws + 8192);    // 24*2*20480 halves = 1966080 B

    hipLaunchKernelGGL(prep_kernel, dim3(240), dim3(256), 0, stream, W, counts, WB);
    hipLaunchKernelGGL(main_kernel, dim3(1024), dim3(512), 0, stream,
                       x, b, noise, cb, WB, out, counts, probsum);
    hipLaunchKernelGGL(fin_kernel, dim3(1), dim3(640), 0, stream, counts, probsum, out + 8388608);
}